// Round 1
// 721.273 us; speedup vs baseline: 1.1036x; 1.1036x over previous
//
#include <hip/hip_runtime.h>
#include <math.h>

#define BATCH 64
#define TIME 400
#define BT (BATCH * TIME)   // 25600
#define S 25                // states
#define CH 80               // channels
#define CD (CH * CH)        // 6400

#define NTHREADS 256
#define CD_TILE (2 * NTHREADS)  // 512 columns per block, 2 per thread
#define ROWS 64                 // bt rows per block

// scale[k] = softplus(alpha_scaling[k]), numerically stable
__global__ void scale_kernel(const float* __restrict__ alpha_scaling,
                             float* __restrict__ scale) {
    int k = threadIdx.x;
    if (k < S) {
        float x = alpha_scaling[k];
        scale[k] = fmaxf(x, 0.0f) + log1pf(expf(-fabsf(x)));
    }
}

// m_t[bt][c] = sum_k alpha[bt][k] * scale[k] * mu[k][c]
// one float4 of output per thread; mu (8 KB) staged in LDS
__global__ __launch_bounds__(NTHREADS) void m_kernel(
    const float* __restrict__ alpha, const float* __restrict__ mu,
    const float* __restrict__ scale, float* __restrict__ out_m) {
    __shared__ float s_mu[S * CH];
    __shared__ float s_scale[S];
    for (int i = threadIdx.x; i < S * CH; i += NTHREADS) s_mu[i] = mu[i];
    if (threadIdx.x < S) s_scale[threadIdx.x] = scale[threadIdx.x];
    __syncthreads();

    int i4 = blockIdx.x * NTHREADS + threadIdx.x;  // float4 index
    const int total4 = BT * CH / 4;
    if (i4 >= total4) return;
    int e = i4 * 4;
    int bt = e / CH;            // CH=80 divisible by 4 -> float4 never crosses a row
    int c = e - bt * CH;
    const float* arow = alpha + (size_t)bt * S;
    float4 acc = {0.f, 0.f, 0.f, 0.f};
#pragma unroll
    for (int k = 0; k < S; k++) {
        float a = arow[k] * s_scale[k];
        float4 m4 = *(const float4*)&s_mu[k * CH + c];
        acc.x += a * m4.x;
        acc.y += a * m4.y;
        acc.z += a * m4.z;
        acc.w += a * m4.w;
    }
    *(float4*)&out_m[e] = acc;
}

// C_t[bt][cd] = sum_k alpha[bt][k]*scale[k] * D[k][cd]
// No LDS. Each thread owns 2 adjacent output columns:
//   d0[k],d1[k] = scale[k]*D[k][c0..c0+1] held in VGPRs (loaded once per block
//   from L2-resident D). The per-row alpha values are block-uniform ->
//   compiler emits s_load into SGPRs; v_fmac consumes the SGPR directly.
// Per row: 25 scalar loads + 50 v_fmac (two interleaved 25-deep FMA chains,
// latency-covered) + 1 coalesced dwordx2 store. Write-roofline bound.
__global__ __launch_bounds__(NTHREADS) void c_kernel(
    const float* __restrict__ alpha, const float* __restrict__ D,
    const float* __restrict__ scale, float* __restrict__ out_c) {
    const int cd0 = blockIdx.x * CD_TILE;     // 13 tiles, last has 256 valid cols
    const int bt0 = blockIdx.y * ROWS;        // 400 tiles
    const int vcols = min(CD_TILE, CD - cd0);
    const int c0 = 2 * (int)threadIdx.x;
    if (c0 >= vcols) return;  // whole trailing waves exit in the partial tile

    // Load this thread's two D columns for all k, scale folded in.
    float d0[S], d1[S];
#pragma unroll
    for (int k = 0; k < S; ++k) {
        float sc = scale[k];  // uniform -> SGPR
        float2 dv = *(const float2*)&D[(size_t)k * CD + cd0 + c0];
        d0[k] = dv.x * sc;
        d1[k] = dv.y * sc;
    }

    const float* arow = alpha + (size_t)bt0 * S;
    float* crow = out_c + (size_t)bt0 * CD + cd0 + c0;
    for (int r = 0; r < ROWS; ++r) {
        float acc0 = 0.f, acc1 = 0.f;
#pragma unroll
        for (int k = 0; k < S; ++k) {
            float a = arow[k];  // block-uniform -> s_load, SGPR operand of fmac
            acc0 = fmaf(a, d0[k], acc0);
            acc1 = fmaf(a, d1[k], acc1);
        }
        float2 v = {acc0, acc1};
        *(float2*)crow = v;
        arow += S;
        crow += CD;
    }
}

extern "C" void kernel_launch(void* const* d_in, const int* in_sizes, int n_in,
                              void* d_out, int out_size, void* d_ws, size_t ws_size,
                              hipStream_t stream) {
    const float* alpha = (const float*)d_in[0];          // [64,400,25]
    const float* mu = (const float*)d_in[1];             // [25,80]
    const float* D = (const float*)d_in[2];              // [25,80,80]
    const float* alpha_scaling = (const float*)d_in[3];  // [25]

    float* out = (float*)d_out;
    float* out_m = out;               // [25600,80]
    float* out_c = out + BT * CH;     // [25600,6400]
    float* scale = (float*)d_ws;      // 25 floats

    scale_kernel<<<1, 64, 0, stream>>>(alpha_scaling, scale);

    const int total4 = BT * CH / 4;  // 512000
    m_kernel<<<(total4 + NTHREADS - 1) / NTHREADS, NTHREADS, 0, stream>>>(
        alpha, mu, scale, out_m);

    dim3 grid((CD + CD_TILE - 1) / CD_TILE, BT / ROWS);  // (13, 400)
    c_kernel<<<grid, NTHREADS, 0, stream>>>(alpha, D, scale, out_c);
}